// Round 10
// baseline (3037.103 us; speedup 1.0000x reference)
//
#include <hip/hip_runtime.h>
#include <stdint.h>

// RNN_6725918786207: 2-layer tanh RNN. B=64, T=512, D_IN=64, D_MODEL=512, D_OUT=64.
// Round 12 = round 11 MFMA engine + handshake fixes. r11 failed correctness; audit
// vs r10's verified skeleton found: (1) B's step-0 prefetch of h0[1] was UNGUARDED
// (r10 bootstrapped fA[0] AND fA[1]; r11 spun only t=0 slabs) -> B consumed garbage
// h0[1] on a cold workspace -> everything downstream wrong. (2) B's in-loop publish
// of fB[509] at step 511 had no covering vmcnt wait (fpre chain ends at step 509).
// Fixes: B prologue spins slab flags at t=0 and t=1; in-loop publish limited to
// t<=510, fB[509..511] published after the full drain; fpre preloads pinned with
// empty asm (r10 idiom). Fragment layouts (verified vs k_gemm), rot=1 slot
// rotation, vmcnt(0)-proven A/C publishes, X0/H1 alias ordering: unchanged.
// Prediction: passed=true; k_rnnm 600-1000us, total 650-1100us; MfmaUtil>0 first
// time; VALUBusy 2-5%; VGPR 150-220 (256 => wB spilled -> asm-pin next round).

typedef unsigned int u32;
typedef unsigned short u16;
typedef unsigned long long u64;
typedef _Float16 f16;
typedef _Float16 v8h __attribute__((ext_vector_type(8)));
typedef float    v4f __attribute__((ext_vector_type(4)));

#define T_STEPS 512
#define DM 512
#define BATCH 64

// ---------- small helpers ----------
__device__ __forceinline__ float f16lo(u32 u) {
    u16 s = (u16)(u & 0xffffu); f16 h; __builtin_memcpy(&h, &s, 2); return (float)h;
}
__device__ __forceinline__ float f16hi(u32 u) {
    u16 s = (u16)(u >> 16); f16 h; __builtin_memcpy(&h, &s, 2); return (float)h;
}
__device__ __forceinline__ u32 packh2(float lo, float hi) {
    f16 a = (f16)lo, b = (f16)hi; u16 ua, ub;
    __builtin_memcpy(&ua, &a, 2); __builtin_memcpy(&ub, &b, 2);
    return (u32)ua | ((u32)ub << 16);
}
__device__ __forceinline__ float tanh_fast(float z) {
    float e = __expf(2.0f * z);
    return 1.0f - 2.0f / (e + 1.0f);
}
// agent-scope (cross-XCD coherent) accesses
__device__ __forceinline__ u32 ld_agent(const u32* p) {
    return __hip_atomic_load(p, __ATOMIC_RELAXED, __HIP_MEMORY_SCOPE_AGENT);
}
__device__ __forceinline__ void st_agent(u32* p, u32 v) {
    __hip_atomic_store(p, v, __ATOMIC_RELAXED, __HIP_MEMORY_SCOPE_AGENT);
}
__device__ __forceinline__ u64 ld_agent64(const u64* p) {
    return __hip_atomic_load(p, __ATOMIC_RELAXED, __HIP_MEMORY_SCOPE_AGENT);
}
__device__ __forceinline__ void st_agent64(u64* p, u64 v) {
    __hip_atomic_store(p, v, __ATOMIC_RELAXED, __HIP_MEMORY_SCOPE_AGENT);
}

// LDS-only barrier (no vmem drain)
#define BARRIER_LG() asm volatile("s_waitcnt lgkmcnt(0)\n\ts_barrier" ::: "memory")

// all-lane bounded spin (wave-uniform address -> no divergence); guard turns a
// coherence surprise into a fast wrong answer instead of a harness hang.
#define SPIN(ptr) do { int g_ = 0;                                                \
    while (!dead && __hip_atomic_load((ptr), __ATOMIC_RELAXED,                    \
                                      __HIP_MEMORY_SCOPE_AGENT) == 0u) {          \
        __builtin_amdgcn_s_sleep(2);                                              \
        if (++g_ > (1 << 21)) dead = 1;                                           \
    } } while (0)

// ---------- prep kernels ----------
__global__ void k_cast_f16(const float* __restrict__ src, f16* __restrict__ dst, int n) {
    int i = blockIdx.x * blockDim.x + threadIdx.x;
    if (i < n) dst[i] = (f16)src[i];
}

// src fp32 [R][C] -> dst fp16 [C][R]
__global__ void k_transpose_f16(const float* __restrict__ src, f16* __restrict__ dst, int R, int C) {
    int i = blockIdx.x * blockDim.x + threadIdx.x;
    if (i < R * C) { int r = i / C, c = i % C; dst[c * R + r] = (f16)src[r * C + c]; }
}

__global__ void k_bias_sum(const float* a0, const float* b0, float* o0,
                           const float* a1, const float* b1, float* o1) {
    int i = blockIdx.x * blockDim.x + threadIdx.x;
    if (i < DM) { o0[i] = a0[i] + b0[i]; o1[i] = a1[i] + b1[i]; }
}

__global__ void k_zero_flags(u32* __restrict__ f, int n) {
    int i = blockIdx.x * blockDim.x + threadIdx.x;
    if (i < n) st_agent(&f[i], 0u);
}

// Pack W [512k][512n] fp32 into MFMA B-fragments (v8h per lane), matching k_gemm's
// verified B layout: lane l supplies n = nt*16+(l&15), k = kt*32+((l>>4)&3)*8 + j.
// Frag slot order per (half,wave): ko 0..15; rot=1 rotates so slots 0..7 are the
// half's OWN k-range (global kt = (hf*8+ko)&15) -> all wB indices compile-time.
__global__ void k_pack_wfrag(const float* __restrict__ W, uint4* __restrict__ WF, int rot) {
    int i = blockIdx.x * 256 + threadIdx.x;    // 32768 = 2hf * 4w * 16ko * 4nt * 64l
    int l  = i & 63;
    int nt = (i >> 6) & 3;
    int ko = (i >> 8) & 15;
    int w  = (i >> 12) & 3;
    int hf = (i >> 14) & 1;
    int kt = rot ? ((hf * 8 + ko) & 15) : ko;
    int n  = hf * 256 + w * 64 + nt * 16 + (l & 15);
    int k0 = kt * 32 + ((l >> 4) & 3) * 8;
    u32 d[4];
    #pragma unroll
    for (int jj = 0; jj < 4; ++jj)
        d[jj] = packh2(W[(size_t)(k0 + 2 * jj) * DM + n], W[(size_t)(k0 + 2 * jj + 1) * DM + n]);
    WF[i] = make_uint4(d[0], d[1], d[2], d[3]);
}

// ---------- MFMA f16 GEMM (unchanged, verified): C = A @ BT^T + bias ----------
__global__ __launch_bounds__(256) void k_gemm(const f16* __restrict__ A, const f16* __restrict__ BT,
                                              void* __restrict__ Cout, const float* __restrict__ bias,
                                              int M, int N, int K, int out_f32) {
    __shared__ f16 As[64][40];
    __shared__ f16 Bs[64][40];
    int tid = threadIdx.x;
    int mb = blockIdx.x, nb = blockIdx.y;
    int l = tid & 63, w = tid >> 6;
    int q = l >> 4, mr = l & 15;

    int sr = tid >> 2;
    int ko = (tid & 3) * 8;
    const f16* gA = A + (size_t)(mb * 64 + sr) * K + ko;
    const f16* gB = BT + (size_t)(nb * 64 + sr) * K + ko;

    v4f acc[4];
    #pragma unroll
    for (int nt = 0; nt < 4; ++nt) acc[nt] = (v4f){0.f, 0.f, 0.f, 0.f};

    for (int kt = 0; kt < K; kt += 32) {
        *(uint4*)&As[sr][ko] = *(const uint4*)(gA + kt);
        *(uint4*)&Bs[sr][ko] = *(const uint4*)(gB + kt);
        __syncthreads();
        v8h a = *(const v8h*)&As[w * 16 + mr][q * 8];
        #pragma unroll
        for (int nt = 0; nt < 4; ++nt) {
            v8h b = *(const v8h*)&Bs[nt * 16 + mr][q * 8];
            acc[nt] = __builtin_amdgcn_mfma_f32_16x16x32_f16(a, b, acc[nt], 0, 0, 0);
        }
        __syncthreads();
    }

    int row0 = mb * 64 + w * 16 + q * 4;
    #pragma unroll
    for (int nt = 0; nt < 4; ++nt) {
        int col = nb * 64 + nt * 16 + mr;
        float bv = bias[col];
        #pragma unroll
        for (int r = 0; r < 4; ++r) {
            float v = acc[nt][r] + bv;
            if (out_f32) ((float*)Cout)[(size_t)(row0 + r) * N + col] = v;
            else         ((f16*)Cout)[(size_t)(row0 + r) * N + col] = (f16)v;
        }
    }
}

// ---------- MFMA 3-stage pipelined recurrence ----------
// grid (16,3): bx&7 >= 4 inactive. hf=bx>>3, g=bx&3, role=by.
//   role 0 (A): h0[t] = tanh(X0[t] + h0[t-1] @ Whh0)  -> H0 (sc1) + per-wave slab flags
//   role 1 (B): x1[t] = h0[t] @ Wih1 + bias1          -> X1 (sc1) + per-WG flag
//   role 2 (C): h1[t] = tanh(x1[t] + h1[t-1] @ Whh1)  -> H1 (sc1) + per-wave slab flags
// Each WG: 256 thr = 4 waves; wave w owns cols hf*256 + w*64..+63 as 64 AGPR-class
// v8h W-frags. Recurrence halves exchange h via slab stores; partner loads are
// consumed in the SECOND MFMA phase so their latency hides under own-k MFMA.
__global__ __launch_bounds__(256, 1) void k_rnnm(const f16* __restrict__ X0,
                                                 f16* __restrict__ H0,
                                                 f16* __restrict__ X1,
                                                 f16* __restrict__ H1,
                                                 const uint4* __restrict__ WF0,
                                                 const uint4* __restrict__ WFI,
                                                 const uint4* __restrict__ WF1,
                                                 const float* __restrict__ bias1,
                                                 u32* __restrict__ fAslab,   // [2hf][4g][4w][T]
                                                 u32* __restrict__ fBwg,     // [2hf][4g][T]
                                                 u32* __restrict__ fCslab) { // [2hf][4g][4w][T]
    int bx = blockIdx.x, role = blockIdx.y;
    if ((bx & 7) >= 4) return;
    int hf = bx >> 3, g = bx & 3;
    int tid = threadIdx.x, l = tid & 63, w = tid >> 6;
    int mr = l & 15, q = (l >> 4) & 3;

    __shared__ f16 hsh[2][16][264];   // rows=batch, cols=local 256 (stride-padded)

    const uint4* WF = (role == 0) ? WF0 : (role == 1) ? WFI : WF1;
    // 64 W-fragments for this wave (used ONLY by MFMA -> AGPR class)
    v8h wB[64];
    {
        const uint4* base = WF + (size_t)(hf * 4 + w) * 4096;
        #pragma unroll
        for (int f = 0; f < 64; ++f) {
            uint4 t4 = base[f * 64 + l];
            __builtin_memcpy(&wB[f], &t4, 16);
        }
    }
    for (int i = tid; i < 2 * 16 * 264 / 2; i += 256) ((u32*)hsh)[i] = 0u;
    __syncthreads();

    int c0 = hf * 256;                 // own global col base
    int lc = w * 64;                   // own local col base (within half)

    if (role == 0) {
        // ---- A: layer-0 recurrence ----
        int dead = 0, cur = 0;
        for (int t = 0; t < T_STEPS; ++t) {
            BARRIER_LG();
            // partner slab flags for h0[t-1] (usually already set)
            if (t > 0) {
                #pragma unroll
                for (int pw = 0; pw < 4; ++pw)
                    SPIN(&fAslab[((((hf ^ 1) * 4 + g) * 4 + pw) * T_STEPS) + (t - 1)]);
            }
            // partner-half A-frags direct from global (consumed in phase 2)
            v8h afp[8];
            if (t > 0) {
                size_t rowb = ((size_t)(g * 16 + mr) * T_STEPS + (t - 1)) * DM;
                #pragma unroll
                for (int j = 0; j < 8; ++j) {
                    size_t k0 = (size_t)((hf ^ 1) * 256 + j * 32 + q * 8);
                    u64 lo = ld_agent64((const u64*)(H0 + rowb + k0));
                    u64 hi = ld_agent64((const u64*)(H0 + rowb + k0 + 4));
                    u32 uu[4] = {(u32)lo, (u32)(lo >> 32), (u32)hi, (u32)(hi >> 32)};
                    __builtin_memcpy(&afp[j], uu, 16);
                }
            } else {
                u32 zz[4] = {0u, 0u, 0u, 0u};
                #pragma unroll
                for (int j = 0; j < 8; ++j) __builtin_memcpy(&afp[j], zz, 16);
            }
            // x0 scalars (plain; X0 written by prior GEMM dispatch)
            f16 xv[4][4];
            #pragma unroll
            for (int nt = 0; nt < 4; ++nt)
                #pragma unroll
                for (int r = 0; r < 4; ++r)
                    xv[nt][r] = X0[((size_t)(g * 16 + q * 4 + r) * T_STEPS + t) * DM
                                   + c0 + lc + nt * 16 + mr];
            // own-half A-frags from LDS
            v8h afo[8];
            #pragma unroll
            for (int j = 0; j < 8; ++j)
                afo[j] = *(const v8h*)&hsh[cur][mr][j * 32 + q * 8];

            v4f acc[4];
            #pragma unroll
            for (int nt = 0; nt < 4; ++nt) acc[nt] = (v4f){0.f, 0.f, 0.f, 0.f};
            #pragma unroll
            for (int j = 0; j < 8; ++j)       // phase 1: own k (LDS, fast)
                #pragma unroll
                for (int nt = 0; nt < 4; ++nt)
                    acc[nt] = __builtin_amdgcn_mfma_f32_16x16x32_f16(afo[j], wB[j * 4 + nt], acc[nt], 0, 0, 0);
            #pragma unroll
            for (int j = 0; j < 8; ++j)       // phase 2: partner k (loads hidden)
                #pragma unroll
                for (int nt = 0; nt < 4; ++nt)
                    acc[nt] = __builtin_amdgcn_mfma_f32_16x16x32_f16(afp[j], wB[(8 + j) * 4 + nt], acc[nt], 0, 0, 0);

            int nxt = cur ^ 1;
            #pragma unroll
            for (int nt = 0; nt < 4; ++nt)
                #pragma unroll
                for (int r = 0; r < 4; ++r) {
                    float z = acc[nt][r] + (float)xv[nt][r];
                    hsh[nxt][q * 4 + r][lc + nt * 16 + mr] = (f16)tanh_fast(z);
                }
            asm volatile("s_waitcnt lgkmcnt(0)" ::: "memory");  // own writes done
            // re-read own 64-col slab contiguously, store sc1 to H0
            #pragma unroll
            for (int j = 0; j < 4; ++j) {
                int u = l * 4 + j;             // 0..255 = 16 rows x 16 chunks(4 cols)
                int row = u >> 4, ch = u & 15;
                u64 v = *(const u64*)&hsh[nxt][row][lc + ch * 4];
                st_agent64((u64*)(H0 + ((size_t)(g * 16 + row) * T_STEPS + t) * DM
                                  + c0 + lc + ch * 4), v);
            }
            asm volatile("s_waitcnt vmcnt(0)" ::: "memory");    // slab visible
            if (l == 0) st_agent(&fAslab[(((hf * 4 + g) * 4 + w) * T_STEPS) + t], 1u);
            cur = nxt;
        }
    } else if (role == 1) {
        // ---- B: x1[t] = h0[t] @ Wih1 + bias1 (feed-forward, prefetched) ----
        int dead = 0;
        float bl[4];
        #pragma unroll
        for (int nt = 0; nt < 4; ++nt) bl[nt] = bias1[c0 + lc + nt * 16 + mr];
        u32* fB = &fBwg[(hf * 4 + g) * T_STEPS];

        // bootstrap: h0[0] AND h0[1] proven before step 0 touches them (r11 bug:
        // step-0 prefetch of h0[1] was unguarded -> garbage on cold workspace)
        #pragma unroll
        for (int sw = 0; sw < 8; ++sw) {
            SPIN(&fAslab[(((sw >> 2) * 4 + g) * 4 + (sw & 3)) * T_STEPS + 0]);
            SPIN(&fAslab[(((sw >> 2) * 4 + g) * 4 + (sw & 3)) * T_STEPS + 1]);
        }
        v8h afc[16], afn[16];
        {
            size_t rowb = ((size_t)(g * 16 + mr) * T_STEPS + 0) * DM;
            #pragma unroll
            for (int j = 0; j < 16; ++j) {
                u64 lo = ld_agent64((const u64*)(H0 + rowb + j * 32 + q * 8));
                u64 hi = ld_agent64((const u64*)(H0 + rowb + j * 32 + q * 8 + 4));
                u32 uu[4] = {(u32)lo, (u32)(lo >> 32), (u32)hi, (u32)(hi >> 32)};
                __builtin_memcpy(&afc[j], uu, 16);
            }
        }
        for (int t = 0; t < T_STEPS; ++t) {
            BARRIER_LG();
            // publish fB[t-2]: proven — stores(t-2) precede (memory-clobber barrier)
            // the fpre loads of step t-1, whose consumption at end of t-1 forced an
            // in-order vmcnt wait. Valid only while the fpre chain exists (t<=510).
            if (tid == 0 && t >= 2 && t <= 510) st_agent(&fB[t - 2], 1u);
            if (t + 1 < T_STEPS) {          // prefetch h0[t+1]; fA[t+1] confirmed:
                                            // t=0 by bootstrap, t>=1 by fpre(t-1)
                size_t rowb = ((size_t)(g * 16 + mr) * T_STEPS + (t + 1)) * DM;
                #pragma unroll
                for (int j = 0; j < 16; ++j) {
                    u64 lo = ld_agent64((const u64*)(H0 + rowb + j * 32 + q * 8));
                    u64 hi = ld_agent64((const u64*)(H0 + rowb + j * 32 + q * 8 + 4));
                    u32 uu[4] = {(u32)lo, (u32)(lo >> 32), (u32)hi, (u32)(hi >> 32)};
                    __builtin_memcpy(&afn[j], uu, 16);
                }
            }
            u32 fpre[8] = {1u, 1u, 1u, 1u, 1u, 1u, 1u, 1u};
            if (t + 2 < T_STEPS) {
                #pragma unroll
                for (int sw = 0; sw < 8; ++sw) {
                    fpre[sw] = ld_agent(&fAslab[(((sw >> 2) * 4 + g) * 4 + (sw & 3)) * T_STEPS + (t + 2)]);
                    asm volatile("" :: "v"(fpre[sw]));   // pin issue point pre-MFMA
                }
            }

            v4f acc[4];
            #pragma unroll
            for (int nt = 0; nt < 4; ++nt) acc[nt] = (v4f){0.f, 0.f, 0.f, 0.f};
            #pragma unroll
            for (int j = 0; j < 16; ++j)
                #pragma unroll
                for (int nt = 0; nt < 4; ++nt)
                    acc[nt] = __builtin_amdgcn_mfma_f32_16x16x32_f16(afc[j], wB[j * 4 + nt], acc[nt], 0, 0, 0);

            #pragma unroll
            for (int nt = 0; nt < 4; ++nt)
                #pragma unroll
                for (int r = 0; r < 4; ++r)
                    hsh[0][q * 4 + r][lc + nt * 16 + mr] = (f16)(acc[nt][r] + bl[nt]);
            BARRIER_LG();                    // all waves' x-share writes visible
            #pragma unroll
            for (int j = 0; j < 4; ++j) {
                int u = tid * 4 + j;         // 0..1023 = 16 rows x 64 chunks(4 cols)
                int row = u >> 6, ch = u & 63;
                u64 v = *(const u64*)&hsh[0][row][ch * 4];
                st_agent64((u64*)(X1 + ((size_t)(g * 16 + row) * T_STEPS + t) * DM
                                  + c0 + ch * 4), v);
            }
            if (t + 2 < T_STEPS) {
                #pragma unroll
                for (int sw = 0; sw < 8; ++sw)
                    if (fpre[sw] == 0u)
                        SPIN(&fAslab[(((sw >> 2) * 4 + g) * 4 + (sw & 3)) * T_STEPS + (t + 2)]);
            }
            if (t + 1 < T_STEPS) {
                #pragma unroll
                for (int j = 0; j < 16; ++j) afc[j] = afn[j];
            }
        }
        __syncthreads();                     // full drain (vmcnt 0): all stores proven
        if (tid == 0) {
            st_agent(&fB[509], 1u); st_agent(&fB[510], 1u); st_agent(&fB[511], 1u);
        }
    } else {
        // ---- C: layer-1 recurrence (A's structure + x1 from B) ----
        int dead = 0, cur = 0;
        u32* fB = &fBwg[(hf * 4 + g) * T_STEPS];
        SPIN(&fB[0]);
        const u32* X1u = (const u32*)X1;
        for (int t = 0; t < T_STEPS; ++t) {
            BARRIER_LG();
            if (t > 0) {
                #pragma unroll
                for (int pw = 0; pw < 4; ++pw)
                    SPIN(&fCslab[((((hf ^ 1) * 4 + g) * 4 + pw) * T_STEPS) + (t - 1)]);
            }
            // x1 scalars (sc1; fB[t] confirmed at end of t-1 / prologue)
            u32 xw[4][4];
            #pragma unroll
            for (int nt = 0; nt < 4; ++nt)
                #pragma unroll
                for (int r = 0; r < 4; ++r) {
                    int col = c0 + lc + nt * 16 + mr;
                    xw[nt][r] = ld_agent(&X1u[(((size_t)(g * 16 + q * 4 + r) * T_STEPS + t) * DM
                                               + (col & ~1)) >> 1]);
                }
            u32 fpre = 1u;
            if (t + 1 < T_STEPS) {
                fpre = ld_agent(&fB[t + 1]);
                asm volatile("" :: "v"(fpre));   // pin issue point pre-MFMA
            }
            v8h afp[8];
            if (t > 0) {
                size_t rowb = ((size_t)(g * 16 + mr) * T_STEPS + (t - 1)) * DM;
                #pragma unroll
                for (int j = 0; j < 8; ++j) {
                    size_t k0 = (size_t)((hf ^ 1) * 256 + j * 32 + q * 8);
                    u64 lo = ld_agent64((const u64*)(H1 + rowb + k0));
                    u64 hi = ld_agent64((const u64*)(H1 + rowb + k0 + 4));
                    u32 uu[4] = {(u32)lo, (u32)(lo >> 32), (u32)hi, (u32)(hi >> 32)};
                    __builtin_memcpy(&afp[j], uu, 16);
                }
            } else {
                u32 zz[4] = {0u, 0u, 0u, 0u};
                #pragma unroll
                for (int j = 0; j < 8; ++j) __builtin_memcpy(&afp[j], zz, 16);
            }
            v8h afo[8];
            #pragma unroll
            for (int j = 0; j < 8; ++j)
                afo[j] = *(const v8h*)&hsh[cur][mr][j * 32 + q * 8];

            v4f acc[4];
            #pragma unroll
            for (int nt = 0; nt < 4; ++nt) acc[nt] = (v4f){0.f, 0.f, 0.f, 0.f};
            #pragma unroll
            for (int j = 0; j < 8; ++j)
                #pragma unroll
                for (int nt = 0; nt < 4; ++nt)
                    acc[nt] = __builtin_amdgcn_mfma_f32_16x16x32_f16(afo[j], wB[j * 4 + nt], acc[nt], 0, 0, 0);
            #pragma unroll
            for (int j = 0; j < 8; ++j)
                #pragma unroll
                for (int nt = 0; nt < 4; ++nt)
                    acc[nt] = __builtin_amdgcn_mfma_f32_16x16x32_f16(afp[j], wB[(8 + j) * 4 + nt], acc[nt], 0, 0, 0);

            int nxt = cur ^ 1;
            #pragma unroll
            for (int nt = 0; nt < 4; ++nt)
                #pragma unroll
                for (int r = 0; r < 4; ++r) {
                    float xf = ((c0 + lc + nt * 16 + mr) & 1) ? f16hi(xw[nt][r]) : f16lo(xw[nt][r]);
                    float z = acc[nt][r] + xf;
                    hsh[nxt][q * 4 + r][lc + nt * 16 + mr] = (f16)tanh_fast(z);
                }
            asm volatile("s_waitcnt lgkmcnt(0)" ::: "memory");
            #pragma unroll
            for (int j = 0; j < 4; ++j) {
                int u = l * 4 + j;
                int row = u >> 4, ch = u & 15;
                u64 v = *(const u64*)&hsh[nxt][row][lc + ch * 4];
                st_agent64((u64*)(H1 + ((size_t)(g * 16 + row) * T_STEPS + t) * DM
                                  + c0 + lc + ch * 4), v);
            }
            asm volatile("s_waitcnt vmcnt(0)" ::: "memory");
            if (l == 0) st_agent(&fCslab[(((hf * 4 + g) * 4 + w) * T_STEPS) + t], 1u);
            if (t + 1 < T_STEPS && fpre == 0u) SPIN(&fB[t + 1]);
            cur = nxt;
        }
    }
}

// ---------- launch ----------
extern "C" void kernel_launch(void* const* d_in, const int* in_sizes, int n_in,
                              void* d_out, int out_size, void* d_ws, size_t ws_size,
                              hipStream_t stream) {
    (void)in_sizes; (void)n_in; (void)out_size; (void)ws_size;
    const float* data = (const float*)d_in[0];
    const float* Wih0 = (const float*)d_in[1];
    const float* bih0 = (const float*)d_in[2];
    const float* Whh0 = (const float*)d_in[3];
    const float* bhh0 = (const float*)d_in[4];
    const float* Wih1 = (const float*)d_in[5];
    const float* bih1 = (const float*)d_in[6];
    const float* Whh1 = (const float*)d_in[7];
    const float* bhh1 = (const float*)d_in[8];
    const float* Wout = (const float*)d_in[9];
    const float* bout = (const float*)d_in[10];

    char* ws = (char*)d_ws;
    // workspace layout (bytes); total = 106,565,632
    f16*   X0    = (f16*)(ws + 0);           // [32768][512] f16; H1 aliased here:
                                             // C stores H1[b][t_C] with t_C lagging
                                             // A's reads of X0[b][t_A] by >=3 slots.
    f16*   H0    = (f16*)(ws + 33554432);    // [32768][512] f16 (A -> B/partner, sc1)
    f16*   X1    = (f16*)(ws + 67108864);    // [32768][512] f16 (B -> C, sc1)
    f16*   D16   = (f16*)(ws + 100663296);   // data fp16 (dead after X0 GEMM)
    u32*   fAslab = (u32*)(ws + 100663296);  // 64 KiB [2][4][4][512] (aliases D16, zeroed post-GEMM)
    u32*   fCslab = (u32*)(ws + 100728832);  // 64 KiB
    u32*   fBwg   = (u32*)(ws + 100794368);  // 16 KiB [2][4][512]
    uint4* WF0   = (uint4*)(ws + 104857600); // Whh0 frags (rot=1), 512 KiB
    uint4* WFI   = (uint4*)(ws + 105381888); // Wih1 frags (rot=0), 512 KiB
    uint4* WF1   = (uint4*)(ws + 105906176); // Whh1 frags (rot=1), 512 KiB
    f16*   WT0   = (f16*)(ws + 106430464);   // Wih0^T [512][64]
    f16*   WoT   = (f16*)(ws + 106496000);   // Wout^T [64][512]
    float* bias0 = (float*)(ws + 106561536);
    float* bias1 = (float*)(ws + 106563584);

    // prep
    k_cast_f16<<<8192, 256, 0, stream>>>(data, D16, 64 * 512 * 64);
    k_pack_wfrag<<<128, 256, 0, stream>>>(Whh0, WF0, 1);
    k_pack_wfrag<<<128, 256, 0, stream>>>(Wih1, WFI, 0);
    k_pack_wfrag<<<128, 256, 0, stream>>>(Whh1, WF1, 1);
    k_transpose_f16<<<128, 256, 0, stream>>>(Wih0, WT0, 64, 512);
    k_transpose_f16<<<128, 256, 0, stream>>>(Wout, WoT, 512, 64);
    k_bias_sum<<<2, 256, 0, stream>>>(bih0, bhh0, bias0, bih1, bhh1, bias1);

    // X0 = data @ Wih0 + bias0  (reads D16, must precede flag zeroing)
    dim3 gX(512, 8);
    k_gemm<<<gX, 256, 0, stream>>>(D16, WT0, (void*)X0, bias0, 32768, 512, 64, 0);

    // zero flag block (fAslab..fBwg contiguous = 36864 words; zero 65536 for margin)
    k_zero_flags<<<256, 256, 0, stream>>>(fAslab, 2 * BATCH * T_STEPS);

    // fused MFMA 3-stage pipeline: 24 active WGs (+24 padding WGs exit instantly)
    k_rnnm<<<dim3(16, 3), 256, 0, stream>>>(X0, H0, X1, X0 /* H1 alias */,
                                            WF0, WFI, WF1, bias1,
                                            fAslab, fBwg, fCslab);

    // OUT = H1 @ Wout + bout -> fp32 d_out
    dim3 gO(512, 1);
    k_gemm<<<gO, 256, 0, stream>>>((const f16*)X0 /* H1 */, WoT, d_out, bout, 32768, 64, 512, 1);
}

// Round 11
// 2768.690 us; speedup vs baseline: 1.0969x; 1.0969x over previous
//
#include <hip/hip_runtime.h>
#include <stdint.h>

// RNN_6725918786207: 2-layer tanh RNN. B=64, T=512, D_IN=64, D_MODEL=512, D_OUT=64.
// Round 13 = r12 MFMA engine (HW-verified correct) + serial-LLC-round-trip cuts.
// r12 counters: slot 5.78us with MFMA busy ~0.2us -> communication-bound. Serial
// costs per step: 4 partner-slab spins (~900cy each, even when set), vmcnt(0)
// drain, exposed partner loads, sleep quantization. Fixes: (1) ONE combined flag
// per WG (end-of-step: per-wave vmcnt(0) -> BARRIER_LG -> tid0 publishes; consumer
// spins once; eager-ack argument unchanged from r12). (2) A/C single barrier per
// step (end only; LDS dbuf ordering proof in comments). (3) SPIN busy-polls 16
// iters before sleeping. B's verified bootstrap/publish kept verbatim modulo the
// flag arrays (2 half-flags instead of 8 slab flags).
// Prediction: slot 5.78 -> 1.5-2.0us; k_rnnm 800-1050us; total 870-1120us;
// MfmaUtil ~2%; VGPR ~220. If slot >= 4us: residual = drain+fabric -> seq-tagged
// data words next. If correctness breaks: revert to r10 (1475us floor).

typedef unsigned int u32;
typedef unsigned short u16;
typedef unsigned long long u64;
typedef _Float16 f16;
typedef _Float16 v8h __attribute__((ext_vector_type(8)));
typedef float    v4f __attribute__((ext_vector_type(4)));

#define T_STEPS 512
#define DM 512
#define BATCH 64

// ---------- small helpers ----------
__device__ __forceinline__ float f16lo(u32 u) {
    u16 s = (u16)(u & 0xffffu); f16 h; __builtin_memcpy(&h, &s, 2); return (float)h;
}
__device__ __forceinline__ float f16hi(u32 u) {
    u16 s = (u16)(u >> 16); f16 h; __builtin_memcpy(&h, &s, 2); return (float)h;
}
__device__ __forceinline__ u32 packh2(float lo, float hi) {
    f16 a = (f16)lo, b = (f16)hi; u16 ua, ub;
    __builtin_memcpy(&ua, &a, 2); __builtin_memcpy(&ub, &b, 2);
    return (u32)ua | ((u32)ub << 16);
}
__device__ __forceinline__ float tanh_fast(float z) {
    float e = __expf(2.0f * z);
    return 1.0f - 2.0f / (e + 1.0f);
}
// agent-scope (cross-XCD coherent) accesses
__device__ __forceinline__ u32 ld_agent(const u32* p) {
    return __hip_atomic_load(p, __ATOMIC_RELAXED, __HIP_MEMORY_SCOPE_AGENT);
}
__device__ __forceinline__ void st_agent(u32* p, u32 v) {
    __hip_atomic_store(p, v, __ATOMIC_RELAXED, __HIP_MEMORY_SCOPE_AGENT);
}
__device__ __forceinline__ u64 ld_agent64(const u64* p) {
    return __hip_atomic_load(p, __ATOMIC_RELAXED, __HIP_MEMORY_SCOPE_AGENT);
}
__device__ __forceinline__ void st_agent64(u64* p, u64 v) {
    __hip_atomic_store(p, v, __ATOMIC_RELAXED, __HIP_MEMORY_SCOPE_AGENT);
}

// LDS-only barrier (no vmem drain)
#define BARRIER_LG() asm volatile("s_waitcnt lgkmcnt(0)\n\ts_barrier" ::: "memory")

// all-lane bounded spin (wave-uniform address -> broadcast, no divergence).
// Busy-polls 16 iterations (removes sleep quantization on the ready path), then
// sleeps. Guard turns a coherence surprise into a fast wrong answer, not a hang.
#define SPIN(ptr) do { int g_ = 0;                                                \
    while (!dead && __hip_atomic_load((ptr), __ATOMIC_RELAXED,                    \
                                      __HIP_MEMORY_SCOPE_AGENT) == 0u) {          \
        if (g_ >= 16) __builtin_amdgcn_s_sleep(2);                                \
        if (++g_ > (1 << 21)) dead = 1;                                           \
    } } while (0)

// ---------- prep kernels ----------
__global__ void k_cast_f16(const float* __restrict__ src, f16* __restrict__ dst, int n) {
    int i = blockIdx.x * blockDim.x + threadIdx.x;
    if (i < n) dst[i] = (f16)src[i];
}

// src fp32 [R][C] -> dst fp16 [C][R]
__global__ void k_transpose_f16(const float* __restrict__ src, f16* __restrict__ dst, int R, int C) {
    int i = blockIdx.x * blockDim.x + threadIdx.x;
    if (i < R * C) { int r = i / C, c = i % C; dst[c * R + r] = (f16)src[r * C + c]; }
}

__global__ void k_bias_sum(const float* a0, const float* b0, float* o0,
                           const float* a1, const float* b1, float* o1) {
    int i = blockIdx.x * blockDim.x + threadIdx.x;
    if (i < DM) { o0[i] = a0[i] + b0[i]; o1[i] = a1[i] + b1[i]; }
}

__global__ void k_zero_flags(u32* __restrict__ f, int n) {
    int i = blockIdx.x * blockDim.x + threadIdx.x;
    if (i < n) st_agent(&f[i], 0u);
}

// Pack W [512k][512n] fp32 into MFMA B-fragments (v8h per lane), matching k_gemm's
// verified B layout: lane l supplies n = nt*16+(l&15), k = kt*32+((l>>4)&3)*8 + j.
// rot=1 rotates so slots 0..7 are the half's OWN k-range (global kt=(hf*8+ko)&15).
__global__ void k_pack_wfrag(const float* __restrict__ W, uint4* __restrict__ WF, int rot) {
    int i = blockIdx.x * 256 + threadIdx.x;    // 32768 = 2hf * 4w * 16ko * 4nt * 64l
    int l  = i & 63;
    int nt = (i >> 6) & 3;
    int ko = (i >> 8) & 15;
    int w  = (i >> 12) & 3;
    int hf = (i >> 14) & 1;
    int kt = rot ? ((hf * 8 + ko) & 15) : ko;
    int n  = hf * 256 + w * 64 + nt * 16 + (l & 15);
    int k0 = kt * 32 + ((l >> 4) & 3) * 8;
    u32 d[4];
    #pragma unroll
    for (int jj = 0; jj < 4; ++jj)
        d[jj] = packh2(W[(size_t)(k0 + 2 * jj) * DM + n], W[(size_t)(k0 + 2 * jj + 1) * DM + n]);
    WF[i] = make_uint4(d[0], d[1], d[2], d[3]);
}

// ---------- MFMA f16 GEMM (unchanged, verified): C = A @ BT^T + bias ----------
__global__ __launch_bounds__(256) void k_gemm(const f16* __restrict__ A, const f16* __restrict__ BT,
                                              void* __restrict__ Cout, const float* __restrict__ bias,
                                              int M, int N, int K, int out_f32) {
    __shared__ f16 As[64][40];
    __shared__ f16 Bs[64][40];
    int tid = threadIdx.x;
    int mb = blockIdx.x, nb = blockIdx.y;
    int l = tid & 63, w = tid >> 6;
    int q = l >> 4, mr = l & 15;

    int sr = tid >> 2;
    int ko = (tid & 3) * 8;
    const f16* gA = A + (size_t)(mb * 64 + sr) * K + ko;
    const f16* gB = BT + (size_t)(nb * 64 + sr) * K + ko;

    v4f acc[4];
    #pragma unroll
    for (int nt = 0; nt < 4; ++nt) acc[nt] = (v4f){0.f, 0.f, 0.f, 0.f};

    for (int kt = 0; kt < K; kt += 32) {
        *(uint4*)&As[sr][ko] = *(const uint4*)(gA + kt);
        *(uint4*)&Bs[sr][ko] = *(const uint4*)(gB + kt);
        __syncthreads();
        v8h a = *(const v8h*)&As[w * 16 + mr][q * 8];
        #pragma unroll
        for (int nt = 0; nt < 4; ++nt) {
            v8h b = *(const v8h*)&Bs[nt * 16 + mr][q * 8];
            acc[nt] = __builtin_amdgcn_mfma_f32_16x16x32_f16(a, b, acc[nt], 0, 0, 0);
        }
        __syncthreads();
    }

    int row0 = mb * 64 + w * 16 + q * 4;
    #pragma unroll
    for (int nt = 0; nt < 4; ++nt) {
        int col = nb * 64 + nt * 16 + mr;
        float bv = bias[col];
        #pragma unroll
        for (int r = 0; r < 4; ++r) {
            float v = acc[nt][r] + bv;
            if (out_f32) ((float*)Cout)[(size_t)(row0 + r) * N + col] = v;
            else         ((f16*)Cout)[(size_t)(row0 + r) * N + col] = (f16)v;
        }
    }
}

// ---------- MFMA 3-stage pipelined recurrence ----------
// grid (16,3): bx&7 >= 4 inactive. hf=bx>>3, g=bx&3, role=by.
//   role 0 (A): h0[t] = tanh(X0[t] + h0[t-1] @ Whh0)  -> H0 (sc1) + combined WG flag
//   role 1 (B): x1[t] = h0[t] @ Wih1 + bias1          -> X1 (sc1) + per-WG flag
//   role 2 (C): h1[t] = tanh(x1[t] + h1[t-1] @ Whh1)  -> H1 (sc1) + combined WG flag
// A/C end-of-step: per-wave vmcnt(0) (write-acks received) -> BARRIER_LG (all 4
// waves proven) -> tid0 publishes ONE flag. Consumers spin once per step.
// A/C have a single barrier per step (end): it orders LDS dbuf writes(t) before
// reads(t+1); writes(t+1) target the opposite buffer whose readers all passed the
// same barrier. B keeps its two barriers (its slab store reads ALL waves' LDS).
__global__ __launch_bounds__(256, 1) void k_rnnm(const f16* __restrict__ X0,
                                                 f16* __restrict__ H0,
                                                 f16* __restrict__ X1,
                                                 f16* __restrict__ H1,
                                                 const uint4* __restrict__ WF0,
                                                 const uint4* __restrict__ WFI,
                                                 const uint4* __restrict__ WF1,
                                                 const float* __restrict__ bias1,
                                                 u32* __restrict__ fA2,     // [2hf][4g][T]
                                                 u32* __restrict__ fBwg,    // [2hf][4g][T]
                                                 u32* __restrict__ fC2) {   // [2hf][4g][T]
    int bx = blockIdx.x, role = blockIdx.y;
    if ((bx & 7) >= 4) return;
    int hf = bx >> 3, g = bx & 3;
    int tid = threadIdx.x, l = tid & 63, w = tid >> 6;
    int mr = l & 15, q = (l >> 4) & 3;

    __shared__ f16 hsh[2][16][264];   // rows=batch, cols=local 256 (stride-padded)

    const uint4* WF = (role == 0) ? WF0 : (role == 1) ? WFI : WF1;
    // 64 W-fragments for this wave (used ONLY by MFMA -> AGPR class)
    v8h wB[64];
    {
        const uint4* base = WF + (size_t)(hf * 4 + w) * 4096;
        #pragma unroll
        for (int f = 0; f < 64; ++f) {
            uint4 t4 = base[f * 64 + l];
            __builtin_memcpy(&wB[f], &t4, 16);
        }
    }
    for (int i = tid; i < 2 * 16 * 264 / 2; i += 256) ((u32*)hsh)[i] = 0u;
    __syncthreads();

    int c0 = hf * 256;                 // own global col base
    int lc = w * 64;                   // own local col base (within half)

    if (role == 0) {
        // ---- A: layer-0 recurrence ----
        int dead = 0, cur = 0;
        for (int t = 0; t < T_STEPS; ++t) {
            // partner combined flag for h0[t-1] (published ~now by partner)
            if (t > 0) SPIN(&fA2[((hf ^ 1) * 4 + g) * T_STEPS + (t - 1)]);
            // partner-half A-frags direct from global (consumed in phase 2)
            v8h afp[8];
            if (t > 0) {
                size_t rowb = ((size_t)(g * 16 + mr) * T_STEPS + (t - 1)) * DM;
                #pragma unroll
                for (int j = 0; j < 8; ++j) {
                    size_t k0 = (size_t)((hf ^ 1) * 256 + j * 32 + q * 8);
                    u64 lo = ld_agent64((const u64*)(H0 + rowb + k0));
                    u64 hi = ld_agent64((const u64*)(H0 + rowb + k0 + 4));
                    u32 uu[4] = {(u32)lo, (u32)(lo >> 32), (u32)hi, (u32)(hi >> 32)};
                    __builtin_memcpy(&afp[j], uu, 16);
                }
            } else {
                u32 zz[4] = {0u, 0u, 0u, 0u};
                #pragma unroll
                for (int j = 0; j < 8; ++j) __builtin_memcpy(&afp[j], zz, 16);
            }
            // x0 scalars (plain; X0 written by prior GEMM dispatch)
            f16 xv[4][4];
            #pragma unroll
            for (int nt = 0; nt < 4; ++nt)
                #pragma unroll
                for (int r = 0; r < 4; ++r)
                    xv[nt][r] = X0[((size_t)(g * 16 + q * 4 + r) * T_STEPS + t) * DM
                                   + c0 + lc + nt * 16 + mr];
            // own-half A-frags from LDS
            v8h afo[8];
            #pragma unroll
            for (int j = 0; j < 8; ++j)
                afo[j] = *(const v8h*)&hsh[cur][mr][j * 32 + q * 8];

            v4f acc[4];
            #pragma unroll
            for (int nt = 0; nt < 4; ++nt) acc[nt] = (v4f){0.f, 0.f, 0.f, 0.f};
            #pragma unroll
            for (int j = 0; j < 8; ++j)       // phase 1: own k (LDS, fast)
                #pragma unroll
                for (int nt = 0; nt < 4; ++nt)
                    acc[nt] = __builtin_amdgcn_mfma_f32_16x16x32_f16(afo[j], wB[j * 4 + nt], acc[nt], 0, 0, 0);
            #pragma unroll
            for (int j = 0; j < 8; ++j)       // phase 2: partner k (loads hidden)
                #pragma unroll
                for (int nt = 0; nt < 4; ++nt)
                    acc[nt] = __builtin_amdgcn_mfma_f32_16x16x32_f16(afp[j], wB[(8 + j) * 4 + nt], acc[nt], 0, 0, 0);

            int nxt = cur ^ 1;
            #pragma unroll
            for (int nt = 0; nt < 4; ++nt)
                #pragma unroll
                for (int r = 0; r < 4; ++r) {
                    float z = acc[nt][r] + (float)xv[nt][r];
                    hsh[nxt][q * 4 + r][lc + nt * 16 + mr] = (f16)tanh_fast(z);
                }
            asm volatile("s_waitcnt lgkmcnt(0)" ::: "memory");  // own-wave writes done
            // re-read own 64-col slab contiguously, store sc1 to H0
            #pragma unroll
            for (int j = 0; j < 4; ++j) {
                int u = l * 4 + j;             // 0..255 = 16 rows x 16 chunks(4 cols)
                int row = u >> 4, ch = u & 15;
                u64 v = *(const u64*)&hsh[nxt][row][lc + ch * 4];
                st_agent64((u64*)(H0 + ((size_t)(g * 16 + row) * T_STEPS + t) * DM
                                  + c0 + lc + ch * 4), v);
            }
            asm volatile("s_waitcnt vmcnt(0)" ::: "memory");    // write-acks received
            BARRIER_LG();                                       // all 4 waves proven
            if (tid == 0) st_agent(&fA2[(hf * 4 + g) * T_STEPS + t], 1u);
            cur = nxt;
        }
    } else if (role == 1) {
        // ---- B: x1[t] = h0[t] @ Wih1 + bias1 (feed-forward, prefetched) ----
        int dead = 0;
        float bl[4];
        #pragma unroll
        for (int nt = 0; nt < 4; ++nt) bl[nt] = bias1[c0 + lc + nt * 16 + mr];
        u32* fB = &fBwg[(hf * 4 + g) * T_STEPS];

        // bootstrap: h0[0] AND h0[1] (both halves) proven before step 0 (r11 bug fix)
        #pragma unroll
        for (int hh = 0; hh < 2; ++hh) {
            SPIN(&fA2[(hh * 4 + g) * T_STEPS + 0]);
            SPIN(&fA2[(hh * 4 + g) * T_STEPS + 1]);
        }
        v8h afc[16], afn[16];
        {
            size_t rowb = ((size_t)(g * 16 + mr) * T_STEPS + 0) * DM;
            #pragma unroll
            for (int j = 0; j < 16; ++j) {
                u64 lo = ld_agent64((const u64*)(H0 + rowb + j * 32 + q * 8));
                u64 hi = ld_agent64((const u64*)(H0 + rowb + j * 32 + q * 8 + 4));
                u32 uu[4] = {(u32)lo, (u32)(lo >> 32), (u32)hi, (u32)(hi >> 32)};
                __builtin_memcpy(&afc[j], uu, 16);
            }
        }
        for (int t = 0; t < T_STEPS; ++t) {
            BARRIER_LG();
            // publish fB[t-2]: proven — stores(t-2) precede the afn loads of step
            // t-1, whose consumption (afc copy) forced an in-order vmcnt wait by
            // the end of t-1; the barrier extends that to all waves. (t<=510: the
            // chain exists only while prefetch does.)
            if (tid == 0 && t >= 2 && t <= 510) st_agent(&fB[t - 2], 1u);
            if (t + 1 < T_STEPS) {          // prefetch h0[t+1]; fA2[.][t+1] confirmed:
                                            // t=0 by bootstrap, t>=1 by fpre(t-1)
                size_t rowb = ((size_t)(g * 16 + mr) * T_STEPS + (t + 1)) * DM;
                #pragma unroll
                for (int j = 0; j < 16; ++j) {
                    u64 lo = ld_agent64((const u64*)(H0 + rowb + j * 32 + q * 8));
                    u64 hi = ld_agent64((const u64*)(H0 + rowb + j * 32 + q * 8 + 4));
                    u32 uu[4] = {(u32)lo, (u32)(lo >> 32), (u32)hi, (u32)(hi >> 32)};
                    __builtin_memcpy(&afn[j], uu, 16);
                }
            }
            u32 fpre[2] = {1u, 1u};
            if (t + 2 < T_STEPS) {
                #pragma unroll
                for (int hh = 0; hh < 2; ++hh) {
                    fpre[hh] = ld_agent(&fA2[(hh * 4 + g) * T_STEPS + (t + 2)]);
                    asm volatile("" :: "v"(fpre[hh]));   // pin issue point pre-MFMA
                }
            }

            v4f acc[4];
            #pragma unroll
            for (int nt = 0; nt < 4; ++nt) acc[nt] = (v4f){0.f, 0.f, 0.f, 0.f};
            #pragma unroll
            for (int j = 0; j < 16; ++j)
                #pragma unroll
                for (int nt = 0; nt < 4; ++nt)
                    acc[nt] = __builtin_amdgcn_mfma_f32_16x16x32_f16(afc[j], wB[j * 4 + nt], acc[nt], 0, 0, 0);

            #pragma unroll
            for (int nt = 0; nt < 4; ++nt)
                #pragma unroll
                for (int r = 0; r < 4; ++r)
                    hsh[0][q * 4 + r][lc + nt * 16 + mr] = (f16)(acc[nt][r] + bl[nt]);
            BARRIER_LG();                    // all waves' x-share writes visible
            #pragma unroll
            for (int j = 0; j < 4; ++j) {
                int u = tid * 4 + j;         // 0..1023 = 16 rows x 64 chunks(4 cols)
                int row = u >> 6, ch = u & 63;
                u64 v = *(const u64*)&hsh[0][row][ch * 4];
                st_agent64((u64*)(X1 + ((size_t)(g * 16 + row) * T_STEPS + t) * DM
                                  + c0 + ch * 4), v);
            }
            if (t + 2 < T_STEPS) {
                #pragma unroll
                for (int hh = 0; hh < 2; ++hh)
                    if (fpre[hh] == 0u)
                        SPIN(&fA2[(hh * 4 + g) * T_STEPS + (t + 2)]);
            }
            if (t + 1 < T_STEPS) {
                #pragma unroll
                for (int j = 0; j < 16; ++j) afc[j] = afn[j];
            }
        }
        __syncthreads();                     // full drain (vmcnt 0): all stores proven
        if (tid == 0) {
            st_agent(&fB[509], 1u); st_agent(&fB[510], 1u); st_agent(&fB[511], 1u);
        }
    } else {
        // ---- C: layer-1 recurrence (A's structure + x1 from B) ----
        int dead = 0, cur = 0;
        u32* fB = &fBwg[(hf * 4 + g) * T_STEPS];
        SPIN(&fB[0]);
        const u32* X1u = (const u32*)X1;
        for (int t = 0; t < T_STEPS; ++t) {
            // partner combined flag for h1[t-1]
            if (t > 0) SPIN(&fC2[((hf ^ 1) * 4 + g) * T_STEPS + (t - 1)]);
            // x1 scalars (sc1; fB[t] confirmed at end of t-1 / prologue)
            u32 xw[4][4];
            #pragma unroll
            for (int nt = 0; nt < 4; ++nt)
                #pragma unroll
                for (int r = 0; r < 4; ++r) {
                    int col = c0 + lc + nt * 16 + mr;
                    xw[nt][r] = ld_agent(&X1u[(((size_t)(g * 16 + q * 4 + r) * T_STEPS + t) * DM
                                               + (col & ~1)) >> 1]);
                }
            u32 fpre = 1u;
            if (t + 1 < T_STEPS) {
                fpre = ld_agent(&fB[t + 1]);
                asm volatile("" :: "v"(fpre));   // pin issue point pre-MFMA
            }
            v8h afp[8];
            if (t > 0) {
                size_t rowb = ((size_t)(g * 16 + mr) * T_STEPS + (t - 1)) * DM;
                #pragma unroll
                for (int j = 0; j < 8; ++j) {
                    size_t k0 = (size_t)((hf ^ 1) * 256 + j * 32 + q * 8);
                    u64 lo = ld_agent64((const u64*)(H1 + rowb + k0));
                    u64 hi = ld_agent64((const u64*)(H1 + rowb + k0 + 4));
                    u32 uu[4] = {(u32)lo, (u32)(lo >> 32), (u32)hi, (u32)(hi >> 32)};
                    __builtin_memcpy(&afp[j], uu, 16);
                }
            } else {
                u32 zz[4] = {0u, 0u, 0u, 0u};
                #pragma unroll
                for (int j = 0; j < 8; ++j) __builtin_memcpy(&afp[j], zz, 16);
            }
            v8h afo[8];
            #pragma unroll
            for (int j = 0; j < 8; ++j)
                afo[j] = *(const v8h*)&hsh[cur][mr][j * 32 + q * 8];

            v4f acc[4];
            #pragma unroll
            for (int nt = 0; nt < 4; ++nt) acc[nt] = (v4f){0.f, 0.f, 0.f, 0.f};
            #pragma unroll
            for (int j = 0; j < 8; ++j)
                #pragma unroll
                for (int nt = 0; nt < 4; ++nt)
                    acc[nt] = __builtin_amdgcn_mfma_f32_16x16x32_f16(afo[j], wB[j * 4 + nt], acc[nt], 0, 0, 0);
            #pragma unroll
            for (int j = 0; j < 8; ++j)
                #pragma unroll
                for (int nt = 0; nt < 4; ++nt)
                    acc[nt] = __builtin_amdgcn_mfma_f32_16x16x32_f16(afp[j], wB[(8 + j) * 4 + nt], acc[nt], 0, 0, 0);

            int nxt = cur ^ 1;
            #pragma unroll
            for (int nt = 0; nt < 4; ++nt)
                #pragma unroll
                for (int r = 0; r < 4; ++r) {
                    float xf = ((c0 + lc + nt * 16 + mr) & 1) ? f16hi(xw[nt][r]) : f16lo(xw[nt][r]);
                    float z = acc[nt][r] + xf;
                    hsh[nxt][q * 4 + r][lc + nt * 16 + mr] = (f16)tanh_fast(z);
                }
            asm volatile("s_waitcnt lgkmcnt(0)" ::: "memory");
            #pragma unroll
            for (int j = 0; j < 4; ++j) {
                int u = l * 4 + j;
                int row = u >> 4, ch = u & 15;
                u64 v = *(const u64*)&hsh[nxt][row][lc + ch * 4];
                st_agent64((u64*)(H1 + ((size_t)(g * 16 + row) * T_STEPS + t) * DM
                                  + c0 + lc + ch * 4), v);
            }
            asm volatile("s_waitcnt vmcnt(0)" ::: "memory");    // write-acks received
            BARRIER_LG();                                       // all 4 waves proven
            if (tid == 0) st_agent(&fC2[(hf * 4 + g) * T_STEPS + t], 1u);
            if (t + 1 < T_STEPS && fpre == 0u) SPIN(&fB[t + 1]);
            cur = nxt;
        }
    }
}

// ---------- launch ----------
extern "C" void kernel_launch(void* const* d_in, const int* in_sizes, int n_in,
                              void* d_out, int out_size, void* d_ws, size_t ws_size,
                              hipStream_t stream) {
    (void)in_sizes; (void)n_in; (void)out_size; (void)ws_size;
    const float* data = (const float*)d_in[0];
    const float* Wih0 = (const float*)d_in[1];
    const float* bih0 = (const float*)d_in[2];
    const float* Whh0 = (const float*)d_in[3];
    const float* bhh0 = (const float*)d_in[4];
    const float* Wih1 = (const float*)d_in[5];
    const float* bih1 = (const float*)d_in[6];
    const float* Whh1 = (const float*)d_in[7];
    const float* bhh1 = (const float*)d_in[8];
    const float* Wout = (const float*)d_in[9];
    const float* bout = (const float*)d_in[10];

    char* ws = (char*)d_ws;
    // workspace layout (bytes); total = 106,565,632
    f16*   X0    = (f16*)(ws + 0);           // [32768][512] f16; H1 aliased here:
                                             // C stores H1[b][t_C] with t_C lagging
                                             // A's reads of X0[b][t_A] by >=3 slots.
    f16*   H0    = (f16*)(ws + 33554432);    // [32768][512] f16 (A -> B/partner, sc1)
    f16*   X1    = (f16*)(ws + 67108864);    // [32768][512] f16 (B -> C, sc1)
    f16*   D16   = (f16*)(ws + 100663296);   // data fp16 (dead after X0 GEMM)
    u32*   fA2   = (u32*)(ws + 100663296);   // 16 KiB [2][4][512] (aliases D16, zeroed post-GEMM)
    u32*   fC2   = (u32*)(ws + 100679680);   // 16 KiB
    u32*   fBwg  = (u32*)(ws + 100696064);   // 16 KiB
    uint4* WF0   = (uint4*)(ws + 104857600); // Whh0 frags (rot=1), 512 KiB
    uint4* WFI   = (uint4*)(ws + 105381888); // Wih1 frags (rot=0), 512 KiB
    uint4* WF1   = (uint4*)(ws + 105906176); // Whh1 frags (rot=1), 512 KiB
    f16*   WT0   = (f16*)(ws + 106430464);   // Wih0^T [512][64]
    f16*   WoT   = (f16*)(ws + 106496000);   // Wout^T [64][512]
    float* bias0 = (float*)(ws + 106561536);
    float* bias1 = (float*)(ws + 106563584);

    // prep
    k_cast_f16<<<8192, 256, 0, stream>>>(data, D16, 64 * 512 * 64);
    k_pack_wfrag<<<128, 256, 0, stream>>>(Whh0, WF0, 1);
    k_pack_wfrag<<<128, 256, 0, stream>>>(Wih1, WFI, 0);
    k_pack_wfrag<<<128, 256, 0, stream>>>(Whh1, WF1, 1);
    k_transpose_f16<<<128, 256, 0, stream>>>(Wih0, WT0, 64, 512);
    k_transpose_f16<<<128, 256, 0, stream>>>(Wout, WoT, 512, 64);
    k_bias_sum<<<2, 256, 0, stream>>>(bih0, bhh0, bias0, bih1, bhh1, bias1);

    // X0 = data @ Wih0 + bias0  (reads D16, must precede flag zeroing)
    dim3 gX(512, 8);
    k_gemm<<<gX, 256, 0, stream>>>(D16, WT0, (void*)X0, bias0, 32768, 512, 64, 0);

    // zero flag block (fA2..fBwg contiguous = 12288 words; zero 65536 for margin)
    k_zero_flags<<<256, 256, 0, stream>>>(fA2, 2 * BATCH * T_STEPS);

    // fused MFMA 3-stage pipeline: 24 active WGs (+24 padding WGs exit instantly)
    k_rnnm<<<dim3(16, 3), 256, 0, stream>>>(X0, H0, X1, X0 /* H1 alias */,
                                            WF0, WFI, WF1, bias1,
                                            fA2, fBwg, fC2);

    // OUT = H1 @ Wout + bout -> fp32 d_out
    dim3 gO(512, 1);
    k_gemm<<<gO, 256, 0, stream>>>((const f16*)X0 /* H1 */, WoT, d_out, bout, 32768, 64, 512, 1);
}

// Round 12
// 1478.493 us; speedup vs baseline: 2.0542x; 1.8726x over previous
//
#include <hip/hip_runtime.h>
#include <stdint.h>

// RNN_6725918786207: 2-layer tanh RNN. B=64, T=512, D_IN=64, D_MODEL=512, D_OUT=64.
// Round 14: restore the session-best kernel (r10: 1475us total, k_rnn3 1412us,
// verified). r11-r13 MFMA arc post-mortem: the cross-WG half-exchange is bound by
// ~4 HBM-class RTTs per recurrence step with zero slack (r13: combined flag cut
// spin count 4->1 yet slot only 5.78->5.28us); MFMA intra-WG is impossible (512KB
// weights = the entire per-CU register file); L2 streaming is bounded by ~135GB/s
// per-CU L2 BW (>=0.95us/step unhidable). r10's intra-WG fdot2 recurrence
// (2.76us/slot vs 2.2us standalone wall) is the best measured structure.
// Structure: 3-stage pipeline across 192 WGs (role A: h0 recurrence; B: x1 =
// h0@Wih1; C: h1 recurrence), hidden flag preloads (checked post-dot), LDS-only
// barriers (no vmem drain), fire-and-forget sc1 data stores, natural-wait flag
// proofs. 216 VGPR shape — no cross-barrier live state (r4/r7/r8 spill law).
// Prediction: k_rnn3 ~1410us, total ~1475us, VGPR 216, VALUBusy ~47%.

typedef unsigned int u32;
typedef unsigned short u16;
typedef _Float16 f16;
typedef _Float16 h2  __attribute__((ext_vector_type(2)));
typedef _Float16 v8h __attribute__((ext_vector_type(8)));
typedef float    v4f __attribute__((ext_vector_type(4)));

#define T_STEPS 512
#define DM 512
#define BATCH 64

// ---------- small helpers ----------
__device__ __forceinline__ float f16lo(u32 u) {
    u16 s = (u16)(u & 0xffffu); f16 h; __builtin_memcpy(&h, &s, 2); return (float)h;
}
__device__ __forceinline__ float f16hi(u32 u) {
    u16 s = (u16)(u >> 16); f16 h; __builtin_memcpy(&h, &s, 2); return (float)h;
}
__device__ __forceinline__ u32 packh2(float lo, float hi) {
    f16 a = (f16)lo, b = (f16)hi; u16 ua, ub;
    __builtin_memcpy(&ua, &a, 2); __builtin_memcpy(&ub, &b, 2);
    return (u32)ua | ((u32)ub << 16);
}
__device__ __forceinline__ float fdot2u(u32 w, u32 h, float acc) {
    h2 a, b; __builtin_memcpy(&a, &w, 4); __builtin_memcpy(&b, &h, 4);
    return __builtin_amdgcn_fdot2(a, b, acc, false);
}
__device__ __forceinline__ u32 RL(u32 v, int l) {
    return (u32)__builtin_amdgcn_readlane((int)v, l);
}
__device__ __forceinline__ float tanh_fast(float z) {
    float e = __expf(2.0f * z);
    return 1.0f - 2.0f / (e + 1.0f);
}
// agent-scope (device/cross-XCD coherent, sc1) dword access
__device__ __forceinline__ u32 ld_agent(const u32* p) {
    return __hip_atomic_load(p, __ATOMIC_RELAXED, __HIP_MEMORY_SCOPE_AGENT);
}
__device__ __forceinline__ void st_agent(u32* p, u32 v) {
    __hip_atomic_store(p, v, __ATOMIC_RELAXED, __HIP_MEMORY_SCOPE_AGENT);
}

// LDS-only barrier: waits DS ops (hbuf double-buffer ordering) but does NOT drain
// vmcnt -> the per-step sc1 data store keeps flying under the next dot.
#define BARRIER_LG() asm volatile("s_waitcnt lgkmcnt(0)\n\ts_barrier" ::: "memory")

// ---------- prep kernels ----------
__global__ void k_cast_f16(const float* __restrict__ src, f16* __restrict__ dst, int n) {
    int i = blockIdx.x * blockDim.x + threadIdx.x;
    if (i < n) dst[i] = (f16)src[i];
}

// W [512][512] fp32 row-major (k-major) -> Wp [256 pair-rows][256 col-pairs] of uint2:
//   Wp[p][c].x = pack(W[2p][2c],   W[2p+1][2c])
//   Wp[p][c].y = pack(W[2p][2c+1], W[2p+1][2c+1])
__global__ void k_pack_whh(const float* __restrict__ W, uint2* __restrict__ Wp) {
    int i = blockIdx.x * blockDim.x + threadIdx.x;  // 65536
    int p = i >> 8, c = i & 255;
    int k0 = 2 * p, j0 = 2 * c;
    uint2 o;
    o.x = packh2(W[k0 * DM + j0],     W[(k0 + 1) * DM + j0]);
    o.y = packh2(W[k0 * DM + j0 + 1], W[(k0 + 1) * DM + j0 + 1]);
    Wp[p * 256 + c] = o;
}

// src fp32 [R][C] -> dst fp16 [C][R]
__global__ void k_transpose_f16(const float* __restrict__ src, f16* __restrict__ dst, int R, int C) {
    int i = blockIdx.x * blockDim.x + threadIdx.x;
    if (i < R * C) { int r = i / C, c = i % C; dst[c * R + r] = (f16)src[r * C + c]; }
}

__global__ void k_bias_sum(const float* a0, const float* b0, float* o0,
                           const float* a1, const float* b1, float* o1) {
    int i = blockIdx.x * blockDim.x + threadIdx.x;
    if (i < DM) { o0[i] = a0[i] + b0[i]; o1[i] = a1[i] + b1[i]; }
}

// zero the handshake flags with agent-scope stores
__global__ void k_zero_flags(u32* __restrict__ f, int n) {
    int i = blockIdx.x * blockDim.x + threadIdx.x;
    if (i < n) st_agent(&f[i], 0u);
}

// ---------- MFMA f16 GEMM: C[M][N] = A[M][K] @ B[K][N] + bias, B given transposed BT[N][K].
__global__ __launch_bounds__(256) void k_gemm(const f16* __restrict__ A, const f16* __restrict__ BT,
                                              void* __restrict__ Cout, const float* __restrict__ bias,
                                              int M, int N, int K, int out_f32) {
    __shared__ f16 As[64][40];
    __shared__ f16 Bs[64][40];
    int tid = threadIdx.x;
    int mb = blockIdx.x, nb = blockIdx.y;
    int l = tid & 63, w = tid >> 6;
    int q = l >> 4, mr = l & 15;

    int sr = tid >> 2;
    int ko = (tid & 3) * 8;
    const f16* gA = A + (size_t)(mb * 64 + sr) * K + ko;
    const f16* gB = BT + (size_t)(nb * 64 + sr) * K + ko;

    v4f acc[4];
    #pragma unroll
    for (int nt = 0; nt < 4; ++nt) acc[nt] = (v4f){0.f, 0.f, 0.f, 0.f};

    for (int kt = 0; kt < K; kt += 32) {
        *(uint4*)&As[sr][ko] = *(const uint4*)(gA + kt);
        *(uint4*)&Bs[sr][ko] = *(const uint4*)(gB + kt);
        __syncthreads();
        v8h a = *(const v8h*)&As[w * 16 + mr][q * 8];
        #pragma unroll
        for (int nt = 0; nt < 4; ++nt) {
            v8h b = *(const v8h*)&Bs[nt * 16 + mr][q * 8];
            acc[nt] = __builtin_amdgcn_mfma_f32_16x16x32_f16(a, b, acc[nt], 0, 0, 0);
        }
        __syncthreads();
    }

    int row0 = mb * 64 + w * 16 + q * 4;
    #pragma unroll
    for (int nt = 0; nt < 4; ++nt) {
        int col = nb * 64 + nt * 16 + mr;
        float bv = bias[col];
        #pragma unroll
        for (int r = 0; r < 4; ++r) {
            float v = acc[nt][r] + bv;
            if (out_f32) ((float*)Cout)[(size_t)(row0 + r) * N + col] = v;
            else         ((f16*)Cout)[(size_t)(row0 + r) * N + col] = (f16)v;
        }
    }
}

// ---------- fused 3-stage pipelined recurrence ----------
// grid (64, 3): blockIdx.x = batch, blockIdx.y = role.
//   role 0 (A): h0[t] = tanh(X0[t] + h0[t-1] @ Whh0)  -> H0 (sc1)
//   role 1 (B): x1[t] = h0[t] @ Wih1 + bias1          -> X1 (sc1)
//   role 2 (C): h1[t] = tanh(x1[t] + h1[t-1] @ Whh1)  -> H1 (plain)
// Per step: BARRIER_LG (LDS wait only) -> flag publish (proof via natural vmem
// waits) -> data loads -> hidden flag PRELOAD for the step after -> dot ->
// store fire-and-forget -> post-dot flag check (spin only if 0; never in steady
// state). No state lives across a barrier. All 192 WGs co-resident (1 WG/CU by
// LDS) -> spins deadlock-free; bounded-spin guard fails fast, not a hang.

#define COMPUTE_DOT() do {                                                        \
    _Pragma("unroll")                                                             \
    for (int p = 0; p < 192; p += 2) {                                            \
        u32 hA = RL(hr[p >> 6], p & 63);                                          \
        u32 hB = RL(hr[(p + 1) >> 6], (p + 1) & 63);                              \
        u32 y0, y1;                                                               \
        asm volatile("v_accvgpr_read_b32 %0, %1" : "=v"(y0) : "a"(w1a[p]));       \
        asm volatile("v_accvgpr_read_b32 %0, %1" : "=v"(y1) : "a"(w1a[p + 1]));   \
        a0 = fdot2u(w0[p], hA, a0);                                               \
        a1 = fdot2u(y0, hA, a1);                                                  \
        a2 = fdot2u(w0[p + 1], hB, a2);                                           \
        a3 = fdot2u(y1, hB, a3);                                                  \
    }                                                                             \
    _Pragma("unroll")                                                             \
    for (int q2 = 0; q2 < 32; ++q2) {                                             \
        uint4 wv = ldsW[q2 * 256 + tid];                                          \
        int p0 = 192 + 2 * q2;                                                    \
        u32 hA = RL(hr[3], p0 & 63);                                              \
        u32 hB = RL(hr[3], (p0 + 1) & 63);                                        \
        a0 = fdot2u(wv.x, hA, a0);                                                \
        a1 = fdot2u(wv.y, hA, a1);                                                \
        a2 = fdot2u(wv.z, hB, a2);                                                \
        a3 = fdot2u(wv.w, hB, a3);                                                \
    }                                                                             \
} while (0)

// tid0-only spin. Bounded: guard turns a coherence surprise into a fast wrong
// answer instead of a harness hang.
#define SPIN(ptr) do { int g_ = 0;                                                \
    while (!dead && __hip_atomic_load((ptr), __ATOMIC_RELAXED,                    \
                                      __HIP_MEMORY_SCOPE_AGENT) == 0u) {          \
        __builtin_amdgcn_s_sleep(2);                                              \
        if (++g_ > (1 << 21)) dead = 1;                                           \
    } } while (0)

__global__ __launch_bounds__(256, 1) void k_rnn3(const u32* __restrict__ X0,
                                                 u32* __restrict__ H0,
                                                 u32* __restrict__ X1,
                                                 u32* __restrict__ H1,
                                                 const uint2* __restrict__ Wp0,
                                                 const uint2* __restrict__ WpI,
                                                 const uint2* __restrict__ Wp1,
                                                 const float* __restrict__ bias1,
                                                 u32* __restrict__ flagA,
                                                 u32* __restrict__ flagB) {
    __shared__ uint4 ldsW[32 * 256];   // 128 KiB: pair-rows 192..255
    __shared__ u32 hbuf[2][256];       // double-buffered recurrent h (roles A, C)

    int b = blockIdx.x, role = blockIdx.y;
    int tid = threadIdx.x, lane = tid & 63;

    const uint2* Wp = (role == 0) ? Wp0 : (role == 1) ? WpI : Wp1;

    // stage LDS-resident part of W
    for (int i = tid; i < 32 * 256; i += 256) {
        int q2 = i >> 8, c = i & 255;
        uint2 lo = Wp[(192 + 2 * q2) * 256 + c];
        uint2 hi = Wp[(193 + 2 * q2) * 256 + c];
        ldsW[i] = make_uint4(lo.x, lo.y, hi.x, hi.y);
    }

    // register-resident part: 192 ArchVGPRs (w0) + 192 AGPRs (w1a)
    u32 w0[192];
    u32 w1a[192];
    #pragma unroll
    for (int p = 0; p < 192; ++p) {
        uint2 t2 = Wp[p * 256 + tid];
        asm volatile("v_mov_b32 %0, %1" : "=v"(w0[p]) : "v"(t2.x));
        asm volatile("v_accvgpr_write_b32 %0, %1" : "=a"(w1a[p]) : "v"(t2.y));
    }

    hbuf[0][tid] = 0u;
    __syncthreads();

    if (role == 0) {
        // ---- A: layer-0 recurrence; store flies under step t+1's dot ----
        const u32* Xb = X0 + (size_t)b * T_STEPS * 256;
        u32* Hb = H0 + (size_t)b * T_STEPS * 256;
        u32* fA = flagA + b * T_STEPS;
        int cur = 0;
        for (int t = 0; t < T_STEPS; ++t) {
            BARRIER_LG();                           // LDS wait only; no vmem drain
            if (tid == 0 && t >= 2) st_agent(&fA[t - 2], 1u);  // proven by xv(t-1) use
            u32 hr[4];
            #pragma unroll
            for (int r = 0; r < 4; ++r) hr[r] = hbuf[cur][r * 64 + lane];
            u32 xv = Xb[t * 256 + tid];             // consumed at end: proves store(t-1)

            float a0 = 0.f, a1 = 0.f, a2 = 0.f, a3 = 0.f;
            COMPUTE_DOT();

            float z0 = a0 + f16lo(xv) + a2;
            float z1 = a1 + f16hi(xv) + a3;
            u32 hp = packh2(tanh_fast(z0), tanh_fast(z1));
            hbuf[cur ^ 1][tid] = hp;
            st_agent(&Hb[t * 256 + tid], hp);       // fire-and-forget
            cur ^= 1;
        }
        __syncthreads();                            // full drain: stores T-2, T-1 proven
        if (tid == 0) { st_agent(&fA[T_STEPS - 2], 1u); st_agent(&fA[T_STEPS - 1], 1u); }
    } else if (role == 1) {
        // ---- B: x1[t] = h0[t] @ Wih1 + bias1; flag check hidden under the dot ----
        const u32* Hb = H0 + (size_t)b * T_STEPS * 256;
        u32* Xb1 = X1 + (size_t)b * T_STEPS * 256;
        u32* fA = flagA + b * T_STEPS;
        u32* fB = flagB + b * T_STEPS;
        float bl = bias1[2 * tid], bh = bias1[2 * tid + 1];
        int dead = 0;

        if (tid == 0) { SPIN(&fA[0]); SPIN(&fA[1]); }   // bootstrap: h0[0], h0[1]
        BARRIER_LG();
        u32 hr[4];
        #pragma unroll
        for (int r = 0; r < 4; ++r) hr[r] = ld_agent(&Hb[r * 64 + lane]);

        for (int t = 0; t < T_STEPS; ++t) {
            BARRIER_LG();
            if (tid == 0 && t >= 2) st_agent(&fB[t - 2], 1u);   // proven by tail vmcnt(1)
            u32 hn[4] = {0u, 0u, 0u, 0u};
            if (t + 1 < T_STEPS) {                  // fA[t+1] confirmed at end of step t-1
                #pragma unroll
                for (int r = 0; r < 4; ++r)
                    hn[r] = ld_agent(&Hb[(size_t)(t + 1) * 256 + r * 64 + lane]);
            }
            u32 fpre = 1u;                          // hidden preload of fA[t+2]
            if (tid == 0 && t + 2 < T_STEPS) {
                fpre = ld_agent(&fA[t + 2]);
                asm volatile("" :: "v"(fpre));      // pin issue point pre-dot
            }

            float a0 = 0.f, a1 = 0.f, a2 = 0.f, a3 = 0.f;
            COMPUTE_DOT();

            u32 xp = packh2(a0 + a2 + bl, a1 + a3 + bh);
            st_agent(&Xb1[t * 256 + tid], xp);      // fire-and-forget
            // leave only the just-issued store outstanding: forces hn(t) returned
            // and (in-order retire) store(t-1) complete — both old, ~0 cost
            asm volatile("s_waitcnt vmcnt(1)" ::: "memory");
            if (tid == 0 && t + 2 < T_STEPS && fpre == 0u) SPIN(&fA[t + 2]);
            #pragma unroll
            for (int r = 0; r < 4; ++r) hr[r] = hn[r];
        }
        __syncthreads();                            // full drain: stores T-2, T-1 proven
        if (tid == 0) { st_agent(&fB[T_STEPS - 2], 1u); st_agent(&fB[T_STEPS - 1], 1u); }
    } else {
        // ---- C: layer-1 recurrence; flag check + xv load hidden under the dot ----
        const u32* Xb1 = X1 + (size_t)b * T_STEPS * 256;
        u32* Hb1 = H1 + (size_t)b * T_STEPS * 256;
        u32* fB = flagB + b * T_STEPS;
        int dead = 0;
        int cur = 0;
        if (tid == 0) SPIN(&fB[0]);                 // bootstrap: x1[0] ready
        for (int t = 0; t < T_STEPS; ++t) {
            BARRIER_LG();
            u32 xv = ld_agent(&Xb1[t * 256 + tid]); // guarded by check at end of t-1
            u32 fpre = 1u;                          // hidden preload of fB[t+1]
            if (tid == 0 && t + 1 < T_STEPS) {
                fpre = ld_agent(&fB[t + 1]);
                asm volatile("" :: "v"(fpre));      // pin issue point pre-dot
            }

            u32 hr[4];
            #pragma unroll
            for (int r = 0; r < 4; ++r) hr[r] = hbuf[cur][r * 64 + lane];

            float a0 = 0.f, a1 = 0.f, a2 = 0.f, a3 = 0.f;
            COMPUTE_DOT();

            float z0 = a0 + f16lo(xv) + a2;
            float z1 = a1 + f16hi(xv) + a3;
            u32 hp = packh2(tanh_fast(z0), tanh_fast(z1));
            hbuf[cur ^ 1][tid] = hp;
            Hb1[t * 256 + tid] = hp;                // plain fire-and-forget
            if (tid == 0 && t + 1 < T_STEPS && fpre == 0u) SPIN(&fB[t + 1]);
            cur ^= 1;
        }
        // final H1 store drained by kernel-end implicit release
    }
}

// ---------- launch ----------
extern "C" void kernel_launch(void* const* d_in, const int* in_sizes, int n_in,
                              void* d_out, int out_size, void* d_ws, size_t ws_size,
                              hipStream_t stream) {
    (void)in_sizes; (void)n_in; (void)out_size; (void)ws_size;
    const float* data = (const float*)d_in[0];
    const float* Wih0 = (const float*)d_in[1];
    const float* bih0 = (const float*)d_in[2];
    const float* Whh0 = (const float*)d_in[3];
    const float* bhh0 = (const float*)d_in[4];
    const float* Wih1 = (const float*)d_in[5];
    const float* bih1 = (const float*)d_in[6];
    const float* Whh1 = (const float*)d_in[7];
    const float* bhh1 = (const float*)d_in[8];
    const float* Wout = (const float*)d_in[9];
    const float* bout = (const float*)d_in[10];

    char* ws = (char*)d_ws;
    // workspace layout (bytes); total = 106,565,632
    f16*   X0    = (f16*)(ws + 0);           // [32768][512] f16; H1 aliased here:
                                             // C writes H1[b][t] only after fB[t] <-
                                             // A far past step t, so A read X0[b][t]
                                             // long before.
    f16*   H0    = (f16*)(ws + 33554432);    // [32768][512] f16 (A -> B, sc1)
    f16*   X1    = (f16*)(ws + 67108864);    // [32768][512] f16 (B -> C, sc1)
    f16*   D16   = (f16*)(ws + 100663296);   // data fp16 [32768][64] (dead after X0 GEMM)
    u32*   flagA = (u32*)(ws + 100663296);   // 128 KiB, aliases D16 head (zeroed post-GEMM)
    u32*   flagB = (u32*)(ws + 100794368);   // 128 KiB
    uint2* Wp0   = (uint2*)(ws + 104857600); // packed Whh0
    uint2* WpI   = (uint2*)(ws + 105381888); // packed Wih1
    uint2* Wp1   = (uint2*)(ws + 105906176); // packed Whh1
    f16*   WT0   = (f16*)(ws + 106430464);   // Wih0^T [512][64]
    f16*   WoT   = (f16*)(ws + 106496000);   // Wout^T [64][512]
    float* bias0 = (float*)(ws + 106561536);
    float* bias1 = (float*)(ws + 106563584);

    // prep
    k_cast_f16<<<8192, 256, 0, stream>>>(data, D16, 64 * 512 * 64);
    k_pack_whh<<<256, 256, 0, stream>>>(Whh0, Wp0);
    k_pack_whh<<<256, 256, 0, stream>>>(Wih1, WpI);
    k_pack_whh<<<256, 256, 0, stream>>>(Whh1, Wp1);
    k_transpose_f16<<<128, 256, 0, stream>>>(Wih0, WT0, 64, 512);
    k_transpose_f16<<<128, 256, 0, stream>>>(Wout, WoT, 512, 64);
    k_bias_sum<<<2, 256, 0, stream>>>(bih0, bhh0, bias0, bih1, bhh1, bias1);

    // X0 = data @ Wih0 + bias0  (reads D16, must precede flag zeroing)
    dim3 gX(512, 8);
    k_gemm<<<gX, 256, 0, stream>>>(D16, WT0, (void*)X0, bias0, 32768, 512, 64, 0);

    // zero flags (flagA..flagB contiguous = 65536 words) with sc1 stores
    k_zero_flags<<<256, 256, 0, stream>>>(flagA, 2 * BATCH * T_STEPS);

    // fused 3-stage pipelined recurrence: 192 WGs, all co-resident
    k_rnn3<<<dim3(64, 3), 256, 0, stream>>>((const u32*)X0, (u32*)H0, (u32*)X1,
                                            (u32*)X0 /* H1 alias */,
                                            Wp0, WpI, Wp1, bias1, flagA, flagB);

    // OUT = H1 @ Wout + bout -> fp32 d_out
    dim3 gO(512, 1);
    k_gemm<<<gO, 256, 0, stream>>>((const f16*)X0 /* H1 */, WoT, d_out, bout, 32768, 64, 512, 1);
}